// Round 3
// baseline (277.393 us; speedup 1.0000x reference)
//
#include <hip/hip_runtime.h>
#include <hip/hip_bf16.h>

// GAT x2 (3 heads, E=2048, batch 0 only) + 2-layer GCN, log_softmax / leaky.
// Non-neighbor exp(-30) terms (~1e-13 vs rowsums ~1e3) are dropped: they
// perturb results by ~1e-10, far below the harness threshold.

// ---------------------------------------------------------------------------
// K1: per-node features. hcol[36][2048] (comp = gat*18 + head*6 + d),
// pack1/pack2 [18][2048]: rows 0..5 = e, 6..11 = exp(e), 12..17 = exp(0.2e)
// Grid 48 = 2 gat x 3 head x 8 node-tiles.
__global__ __launch_bounds__(256) void k1_features(
    const float* __restrict__ node, const float* __restrict__ uv,
    const float* __restrict__ Wt1, const float* __restrict__ at1,
    const float* __restrict__ Wt2, const float* __restrict__ at2,
    float* __restrict__ hcol, float* __restrict__ pack1, float* __restrict__ pack2) {
  __shared__ float sW[192];
  __shared__ float sA[12];
  int b = blockIdx.x;
  int g = b / 24;
  int h = (b / 8) % 3;
  int e = (b % 8) * 256 + threadIdx.x;
  const float* W = (g ? Wt2 : Wt1) + h * 192;
  const float* A = (g ? at2 : at1) + h * 12;
  const float* x = (g ? uv : node) + e * 32;
  if (threadIdx.x < 192) sW[threadIdx.x] = W[threadIdx.x];
  if (threadIdx.x < 12) sA[threadIdx.x] = A[threadIdx.x];
  __syncthreads();
  float xv[32];
#pragma unroll
  for (int i = 0; i < 32; ++i) xv[i] = x[i];
  float hv[6];
#pragma unroll
  for (int d = 0; d < 6; ++d) hv[d] = 0.f;
#pragma unroll
  for (int i = 0; i < 32; ++i)
#pragma unroll
    for (int d = 0; d < 6; ++d) hv[d] += xv[i] * sW[i * 6 + d];
  float e1 = 0.f, e2 = 0.f;
#pragma unroll
  for (int d = 0; d < 6; ++d) {
    e1 += hv[d] * sA[d];
    e2 += hv[d] * sA[6 + d];
  }
  int c = g * 3 + h;
#pragma unroll
  for (int d = 0; d < 6; ++d) hcol[(c * 6 + d) * 2048 + e] = hv[d];
  pack1[c * 2048 + e] = e1;
  pack1[(6 + c) * 2048 + e] = __expf(e1);
  pack1[(12 + c) * 2048 + e] = __expf(0.2f * e1);
  pack2[c * 2048 + e] = e2;
  pack2[(6 + c) * 2048 + e] = __expf(e2);
  pack2[(12 + c) * 2048 + e] = __expf(0.2f * e2);
}

// ---------------------------------------------------------------------------
// K2: invrs[c][i] = 1 / sum_j w(i,j,c), w = adj * (pos? p1*p2 : q1*q2).
// Block 384 (wave = comp c), 4 rows per block, lanes sweep j via float4.
__global__ __launch_bounds__(384) void k2_rowsum(
    const float* __restrict__ adj0, const float* __restrict__ pack1,
    const float* __restrict__ pack2, float* __restrict__ invrs) {
  int tid = threadIdx.x;
  int c = tid >> 6, lane = tid & 63;
  int i0 = blockIdx.x * 4;
  const float4* adj4 = (const float4*)adj0;
  const float4* p2_4 = (const float4*)pack2;
  float e1r[4], p1r[4], q1r[4], sum[4];
#pragma unroll
  for (int r = 0; r < 4; ++r) {
    e1r[r] = pack1[c * 2048 + i0 + r];
    p1r[r] = pack1[(6 + c) * 2048 + i0 + r];
    q1r[r] = pack1[(12 + c) * 2048 + i0 + r];
    sum[r] = 0.f;
  }
#pragma unroll
  for (int it = 0; it < 8; ++it) {
    int j4 = it * 64 + lane;  // float4 index into a 2048-row
    float4 e2 = p2_4[c * 512 + j4];
    float4 p2 = p2_4[(6 + c) * 512 + j4];
    float4 q2 = p2_4[(12 + c) * 512 + j4];
    float4 av[4];
#pragma unroll
    for (int r = 0; r < 4; ++r) av[r] = adj4[(i0 + r) * 512 + j4];
#pragma unroll
    for (int r = 0; r < 4; ++r) {
      float s0, s1, s2, s3;
      {
        float e = e1r[r] + e2.x; bool p = e > 0.f;
        s0 = av[r].x * (p ? p1r[r] : q1r[r]) * (p ? p2.x : q2.x);
      }
      {
        float e = e1r[r] + e2.y; bool p = e > 0.f;
        s1 = av[r].y * (p ? p1r[r] : q1r[r]) * (p ? p2.y : q2.y);
      }
      {
        float e = e1r[r] + e2.z; bool p = e > 0.f;
        s2 = av[r].z * (p ? p1r[r] : q1r[r]) * (p ? p2.z : q2.z);
      }
      {
        float e = e1r[r] + e2.w; bool p = e > 0.f;
        s3 = av[r].w * (p ? p1r[r] : q1r[r]) * (p ? p2.w : q2.w);
      }
      sum[r] += (s0 + s1) + (s2 + s3);
    }
  }
#pragma unroll
  for (int r = 0; r < 4; ++r) {
#pragma unroll
    for (int off = 32; off > 0; off >>= 1) sum[r] += __shfl_down(sum[r], off);
  }
  if (lane == 0) {
#pragma unroll
    for (int r = 0; r < 4; ++r) invrs[c * 2048 + i0 + r] = 1.0f / sum[r];
  }
}

// ---------------------------------------------------------------------------
// K3: hp_part[s][k][j] = sum_{i in split s} w(i,j,c) * (h[i,k]*invrs[c][i]).
// Block 384 (wave = comp c, lanes = 64 j). Grid (32 j-tiles, nsplit).
__global__ __launch_bounds__(384) void k3_hprime(
    const float* __restrict__ adj0, const float* __restrict__ hcol,
    const float* __restrict__ pack1, const float* __restrict__ pack2,
    const float* __restrict__ invrs, float* __restrict__ hp_part, int ipers) {
  __shared__ float sAdj[64 * 64];
  __shared__ float4 sPack[6 * 64];   // e1, p1, q1, 0
  __shared__ float sHS[6 * 64 * 8];  // scaled h, 6 used + 2 pad
  float4* sAdj4 = (float4*)sAdj;
  const float4* adj4 = (const float4*)adj0;
  float4* sHS4 = (float4*)sHS;
  int tid = threadIdx.x;
  int c6 = tid >> 6, jl = tid & 63;
  int j0 = blockIdx.x * 64;
  int j = j0 + jl;
  int s = blockIdx.y;
  float e2v = pack2[c6 * 2048 + j];
  float p2v = pack2[(6 + c6) * 2048 + j];
  float q2v = pack2[(12 + c6) * 2048 + j];
  float acc0 = 0.f, acc1 = 0.f, acc2 = 0.f, acc3 = 0.f, acc4 = 0.f, acc5 = 0.f;
  int ibeg = s * ipers, iend = ibeg + ipers;
  for (int i0 = ibeg; i0 < iend; i0 += 64) {
    __syncthreads();
    for (int idx = tid; idx < 1024; idx += 384) {
      int ii = idx >> 4, c4 = idx & 15;
      sAdj4[ii * 16 + c4] = adj4[(i0 + ii) * 512 + (j0 >> 2) + c4];
    }
    {
      int cc = c6, ii = jl;
      float e1 = pack1[cc * 2048 + i0 + ii];
      float p1 = pack1[(6 + cc) * 2048 + i0 + ii];
      float q1 = pack1[(12 + cc) * 2048 + i0 + ii];
      sPack[cc * 64 + ii] = make_float4(e1, p1, q1, 0.f);
      float iv = invrs[cc * 2048 + i0 + ii];
#pragma unroll
      for (int d = 0; d < 6; ++d)
        sHS[(cc * 64 + ii) * 8 + d] = hcol[(cc * 6 + d) * 2048 + i0 + ii] * iv;
      sHS[(cc * 64 + ii) * 8 + 6] = 0.f;
      sHS[(cc * 64 + ii) * 8 + 7] = 0.f;
    }
    __syncthreads();
#pragma unroll 8
    for (int ii = 0; ii < 64; ++ii) {
      float adjv = sAdj[ii * 64 + jl];
      float4 pk = sPack[c6 * 64 + ii];
      float4 h0 = sHS4[(c6 * 64 + ii) * 2];
      float4 h1 = sHS4[(c6 * 64 + ii) * 2 + 1];
      float e = pk.x + e2v;
      bool pos = e > 0.f;
      float w = adjv * (pos ? pk.y : pk.z) * (pos ? p2v : q2v);
      acc0 += w * h0.x;
      acc1 += w * h0.y;
      acc2 += w * h0.z;
      acc3 += w * h0.w;
      acc4 += w * h1.x;
      acc5 += w * h1.y;
    }
  }
  int kb = c6 * 6;
  hp_part[(s * 36 + kb + 0) * 2048 + j] = acc0;
  hp_part[(s * 36 + kb + 1) * 2048 + j] = acc1;
  hp_part[(s * 36 + kb + 2) * 2048 + j] = acc2;
  hp_part[(s * 36 + kb + 3) * 2048 + j] = acc3;
  hp_part[(s * 36 + kb + 4) * 2048 + j] = acc4;
  hp_part[(s * 36 + kb + 5) * 2048 + j] = acc5;
}

// ---------------------------------------------------------------------------
// K4: merge partials -> hp[j][36], elu, then T[j][32] = {hcY@Wg1, hcO@Wo1}.
__global__ __launch_bounds__(256) void k4_T(
    const float* __restrict__ hp_part, const float* __restrict__ Wg1,
    const float* __restrict__ Wo1, float* __restrict__ T, int nsplit) {
  __shared__ float sHP[64 * 37];
  __shared__ float sWg[288], sWo[288];
  int tid = threadIdx.x;
  int j0 = blockIdx.x * 64;
  for (int idx = tid; idx < 288; idx += 256) {
    sWg[idx] = Wg1[idx];
    sWo[idx] = Wo1[idx];
  }
  for (int idx = tid; idx < 2304; idx += 256) {
    int r = idx >> 6, jl = idx & 63;
    float s = 0.f;
    for (int sp = 0; sp < nsplit; ++sp)
      s += hp_part[(sp * 36 + r) * 2048 + j0 + jl];
    sHP[jl * 37 + r] = s;
  }
  __syncthreads();
  int jl = tid & 63, wq = tid >> 6;
  int gat = wq >> 1;
  int c0 = (wq & 1) * 8;
  const float* Wp = gat ? sWo : sWg;
  float acc[8];
#pragma unroll
  for (int t = 0; t < 8; ++t) acc[t] = 0.f;
#pragma unroll
  for (int r = 0; r < 18; ++r) {
    float x = sHP[jl * 37 + gat * 18 + r];
    float hc = x > 0.f ? x : __expf(x) - 1.f;
#pragma unroll
    for (int t = 0; t < 8; ++t) acc[t] += hc * Wp[r * 16 + c0 + t];
  }
#pragma unroll
  for (int t = 0; t < 8; ++t) T[(j0 + jl) * 32 + gat * 16 + c0 + t] = acc[t];
}

// ---------------------------------------------------------------------------
// K5: Craw_part[s] = a0[:, ksplit s] @ T[ksplit s]  (64 rows x kw cols / block).
// Transposed k-major adj tile in LDS (stride 65: conflict-free both sides).
__global__ __launch_bounds__(256) void k5_gcn1(
    const float* __restrict__ adj0, const float* __restrict__ T,
    float* __restrict__ Craw_part, int kw) {
  __shared__ float sAtT[64 * 65];  // [k][row]
  __shared__ float sT[64 * 32];    // [k][c]
  float4* sT4 = (float4*)sT;
  const float4* adj4 = (const float4*)adj0;
  const float4* T4 = (const float4*)T;
  int tid = threadIdx.x;
  int row = tid & 63, cg = tid >> 6;
  int i0 = blockIdx.x * 64;
  int s = blockIdx.y;
  int k0 = s * kw;
  float acc[8];
#pragma unroll
  for (int t = 0; t < 8; ++t) acc[t] = 0.f;
  for (int kb = k0; kb < k0 + kw; kb += 64) {
    __syncthreads();
    // stage adj tile transposed: thread -> (r = idx>>4, kq = idx&15)
    for (int idx = tid; idx < 1024; idx += 256) {
      int r = idx >> 4, kq = idx & 15;
      float4 a = adj4[(i0 + r) * 512 + (kb >> 2) + kq];
      sAtT[(kq * 4 + 0) * 65 + r] = a.x;
      sAtT[(kq * 4 + 1) * 65 + r] = a.y;
      sAtT[(kq * 4 + 2) * 65 + r] = a.z;
      sAtT[(kq * 4 + 3) * 65 + r] = a.w;
    }
    for (int idx = tid; idx < 512; idx += 256) sT4[idx] = T4[kb * 8 + idx];
    __syncthreads();
#pragma unroll 16
    for (int k = 0; k < 64; ++k) {
      float a = sAtT[k * 65 + row];
      float4 t0 = sT4[k * 8 + cg * 2];
      float4 t1 = sT4[k * 8 + cg * 2 + 1];
      acc[0] += a * t0.x;
      acc[1] += a * t0.y;
      acc[2] += a * t0.z;
      acc[3] += a * t0.w;
      acc[4] += a * t1.x;
      acc[5] += a * t1.y;
      acc[6] += a * t1.z;
      acc[7] += a * t1.w;
    }
  }
  float4* out4 = (float4*)&Craw_part[(long)s * 65536 + (i0 + row) * 32 + cg * 8];
  out4[0] = make_float4(acc[0], acc[1], acc[2], acc[3]);
  out4[1] = make_float4(acc[4], acc[5], acc[6], acc[7]);
}

// ---------------------------------------------------------------------------
// K6: merge Craw partials, +bias, relu, @Wg2/@Wo2 -> T2[j][4].
__global__ __launch_bounds__(256) void k6_T2(
    const float* __restrict__ Craw_part, const float* __restrict__ bg1,
    const float* __restrict__ Wg2, const float* __restrict__ bo1,
    const float* __restrict__ Wo2, float* __restrict__ T2, int n5) {
  __shared__ float sCr[64 * 33];
  __shared__ float sB[32], sW2[64];
  int tid = threadIdx.x;
  int j0 = blockIdx.x * 64;
  if (tid < 16) sB[tid] = bg1[tid];
  else if (tid < 32) sB[tid] = bo1[tid - 16];
  else if (tid < 64) sW2[tid - 32] = Wg2[tid - 32];
  else if (tid < 96) sW2[tid - 32] = Wo2[tid - 64];
  for (int idx = tid; idx < 2048; idx += 256) {
    int jl = idx >> 5, cc = idx & 31;
    float s = 0.f;
    for (int sp = 0; sp < n5; ++sp)
      s += Craw_part[(long)sp * 65536 + (j0 + jl) * 32 + cc];
    sCr[jl * 33 + cc] = s;
  }
  __syncthreads();
  int jl = tid & 63, slot = tid >> 6;
  int gat = slot >> 1, col = slot & 1;
  float v = 0.f;
#pragma unroll
  for (int cc = 0; cc < 16; ++cc) {
    float x = sCr[jl * 33 + gat * 16 + cc] + sB[gat * 16 + cc];
    x = x > 0.f ? x : 0.f;
    v += x * sW2[gat * 32 + cc * 2 + col];
  }
  T2[(j0 + jl) * 4 + slot] = v;
}

// ---------------------------------------------------------------------------
// K7: final a0 @ T2 (+bias), log_softmax(axis=1) + leaky(0.01).
// Wave per row, no LDS (T2 is L2-hot), grid 512.
__global__ __launch_bounds__(256) void k7_final(
    const float* __restrict__ adj0, const float* __restrict__ T2,
    const float* __restrict__ bg2, const float* __restrict__ bo2,
    float* __restrict__ out) {
  int tid = threadIdx.x;
  int lane = tid & 63, w = tid >> 6;
  int r = blockIdx.x * 4 + w;
  const float4* adj4 = (const float4*)adj0;
  const float4* T24 = (const float4*)T2;
  float4 acc = make_float4(0.f, 0.f, 0.f, 0.f);
#pragma unroll
  for (int it = 0; it < 8; ++it) {
    int k4 = it * 64 + lane;  // float4 index: covers k = 4*k4 .. 4*k4+3
    float4 av = adj4[r * 512 + k4];
    float4 t0 = T24[k4 * 4 + 0];
    float4 t1 = T24[k4 * 4 + 1];
    float4 t2 = T24[k4 * 4 + 2];
    float4 t3 = T24[k4 * 4 + 3];
    acc.x += av.x * t0.x + av.y * t1.x + av.z * t2.x + av.w * t3.x;
    acc.y += av.x * t0.y + av.y * t1.y + av.z * t2.y + av.w * t3.y;
    acc.z += av.x * t0.z + av.y * t1.z + av.z * t2.z + av.w * t3.z;
    acc.w += av.x * t0.w + av.y * t1.w + av.z * t2.w + av.w * t3.w;
  }
#pragma unroll
  for (int off = 32; off > 0; off >>= 1) {
    acc.x += __shfl_down(acc.x, off);
    acc.y += __shfl_down(acc.y, off);
    acc.z += __shfl_down(acc.z, off);
    acc.w += __shfl_down(acc.w, off);
  }
  if (lane == 0) {
    float y0 = acc.x + bg2[0], y1 = acc.y + bg2[1];
    float m = fmaxf(y0, y1);
    float ls = m + logf(__expf(y0 - m) + __expf(y1 - m));
    out[r * 2 + 0] = y0 - ls;
    out[r * 2 + 1] = y1 - ls;
    float o0 = acc.z + bo2[0], o1 = acc.w + bo2[1];
    out[4096 + r * 2 + 0] = o0 > 0.f ? o0 : 0.01f * o0;
    out[4096 + r * 2 + 1] = o1 > 0.f ? o1 : 0.01f * o1;
  }
}

extern "C" void kernel_launch(void* const* d_in, const int* in_sizes, int n_in,
                              void* d_out, int out_size, void* d_ws, size_t ws_size,
                              hipStream_t stream) {
  const float* node = (const float*)d_in[0];
  const float* uv = (const float*)d_in[1];
  const float* adj = (const float*)d_in[2];  // batch 0 = first 2048*2048
  const float* Wt1 = (const float*)d_in[3];
  const float* at1 = (const float*)d_in[4];
  const float* Wt2 = (const float*)d_in[5];
  const float* at2 = (const float*)d_in[6];
  const float* Wg1 = (const float*)d_in[7];
  const float* bg1 = (const float*)d_in[8];
  const float* Wg2 = (const float*)d_in[9];
  const float* bg2 = (const float*)d_in[10];
  const float* Wo1 = (const float*)d_in[11];
  const float* bo1 = (const float*)d_in[12];
  const float* Wo2 = (const float*)d_in[13];
  const float* bo2 = (const float*)d_in[14];
  float* ws = (float*)d_ws;
  float* hcol = ws;                  // 73728
  float* pack1 = ws + 73728;         // 36864
  float* pack2 = ws + 110592;        // 36864
  float* invrs = ws + 147456;        // 12288
  float* T = ws + 159744;            // 65536
  float* T2 = ws + 225280;           // 8192
  float* hp_part = ws + 233472;      // n3 * 73728
  float* out = (float*)d_out;

  long wsf = (long)(ws_size / 4);
  long avail = wsf - 233472L;
  // k3 split count (needs n3*73728 + at least 1*65536 for Craw)
  int n3 = 1;
  for (int c = 16; c >= 1; c >>= 1)
    if (avail >= (long)c * 73728 + 65536) { n3 = c; break; }
  long craw_off = 233472L + (long)n3 * 73728;
  long avail5 = wsf - craw_off;
  int n5 = 1;
  for (int c = 32; c >= 1; c >>= 1)
    if (avail5 >= (long)c * 65536) { n5 = c; break; }
  float* Craw_part = ws + craw_off;
  int ipers = 2048 / n3;
  int kw = 2048 / n5;

  k1_features<<<48, 256, 0, stream>>>(node, uv, Wt1, at1, Wt2, at2, hcol, pack1, pack2);
  k2_rowsum<<<512, 384, 0, stream>>>(adj, pack1, pack2, invrs);
  k3_hprime<<<dim3(32, n3), 384, 0, stream>>>(adj, hcol, pack1, pack2, invrs, hp_part, ipers);
  k4_T<<<32, 256, 0, stream>>>(hp_part, Wg1, Wo1, T, n3);
  k5_gcn1<<<dim3(32, n5), 256, 0, stream>>>(adj, T, Craw_part, kw);
  k6_T2<<<32, 256, 0, stream>>>(Craw_part, bg1, Wg2, bo1, Wo2, T2, n5);
  k7_final<<<512, 256, 0, stream>>>(adj, T2, bg2, bo2, out);
}

// Round 4
// 208.750 us; speedup vs baseline: 1.3288x; 1.3288x over previous
//
#include <hip/hip_runtime.h>
#include <hip/hip_bf16.h>

// GAT x2 (3 heads, E=2048, batch 0 only) + 2-layer GCN, log_softmax / leaky.
// Non-neighbor exp(-30) terms (~1e-13 vs rowsums ~O(1e3)) are dropped: they
// perturb results ~1e-10, far below threshold.
// Split-K merging is done with device-scope f32 atomics (no partial buffers,
// no tiny-grid merge kernels -- those were latency-bound at <2% occupancy).

// ---------------------------------------------------------------------------
// K1: per-node features. hcol[36][2048] (comp = gat*18 + head*6 + d),
// pack1/pack2 [18][2048]: rows 0..5 = e, 6..11 = exp(e), 12..17 = exp(0.2e)
__global__ __launch_bounds__(256) void k1_features(
    const float* __restrict__ node, const float* __restrict__ uv,
    const float* __restrict__ Wt1, const float* __restrict__ at1,
    const float* __restrict__ Wt2, const float* __restrict__ at2,
    float* __restrict__ hcol, float* __restrict__ pack1, float* __restrict__ pack2) {
  __shared__ float sW[192];
  __shared__ float sA[12];
  int b = blockIdx.x;
  int g = b / 24;
  int h = (b / 8) % 3;
  int e = (b % 8) * 256 + threadIdx.x;
  const float* W = (g ? Wt2 : Wt1) + h * 192;
  const float* A = (g ? at2 : at1) + h * 12;
  const float* x = (g ? uv : node) + e * 32;
  if (threadIdx.x < 192) sW[threadIdx.x] = W[threadIdx.x];
  if (threadIdx.x < 12) sA[threadIdx.x] = A[threadIdx.x];
  __syncthreads();
  float xv[32];
#pragma unroll
  for (int i = 0; i < 32; ++i) xv[i] = x[i];
  float hv[6];
#pragma unroll
  for (int d = 0; d < 6; ++d) hv[d] = 0.f;
#pragma unroll
  for (int i = 0; i < 32; ++i)
#pragma unroll
    for (int d = 0; d < 6; ++d) hv[d] += xv[i] * sW[i * 6 + d];
  float e1 = 0.f, e2 = 0.f;
#pragma unroll
  for (int d = 0; d < 6; ++d) {
    e1 += hv[d] * sA[d];
    e2 += hv[d] * sA[6 + d];
  }
  int c = g * 3 + h;
#pragma unroll
  for (int d = 0; d < 6; ++d) hcol[(c * 6 + d) * 2048 + e] = hv[d];
  pack1[c * 2048 + e] = e1;
  pack1[(6 + c) * 2048 + e] = __expf(e1);
  pack1[(12 + c) * 2048 + e] = __expf(0.2f * e1);
  pack2[c * 2048 + e] = e2;
  pack2[(6 + c) * 2048 + e] = __expf(e2);
  pack2[(12 + c) * 2048 + e] = __expf(0.2f * e2);
}

// ---------------------------------------------------------------------------
// K2: invrs[c][i] = 1 / sum_j w(i,j,c), w = adj * (pos? p1*p2 : q1*q2).
// Block 384 (wave = comp c), 4 rows per block, lanes sweep j via float4.
__global__ __launch_bounds__(384) void k2_rowsum(
    const float* __restrict__ adj0, const float* __restrict__ pack1,
    const float* __restrict__ pack2, float* __restrict__ invrs) {
  int tid = threadIdx.x;
  int c = tid >> 6, lane = tid & 63;
  int i0 = blockIdx.x * 4;
  const float4* adj4 = (const float4*)adj0;
  const float4* p2_4 = (const float4*)pack2;
  float e1r[4], p1r[4], q1r[4], sum[4];
#pragma unroll
  for (int r = 0; r < 4; ++r) {
    e1r[r] = pack1[c * 2048 + i0 + r];
    p1r[r] = pack1[(6 + c) * 2048 + i0 + r];
    q1r[r] = pack1[(12 + c) * 2048 + i0 + r];
    sum[r] = 0.f;
  }
#pragma unroll
  for (int it = 0; it < 8; ++it) {
    int j4 = it * 64 + lane;
    float4 e2 = p2_4[c * 512 + j4];
    float4 p2 = p2_4[(6 + c) * 512 + j4];
    float4 q2 = p2_4[(12 + c) * 512 + j4];
    float4 av[4];
#pragma unroll
    for (int r = 0; r < 4; ++r) av[r] = adj4[(i0 + r) * 512 + j4];
#pragma unroll
    for (int r = 0; r < 4; ++r) {
      float s0, s1, s2, s3;
      { float e = e1r[r] + e2.x; bool p = e > 0.f;
        s0 = av[r].x * (p ? p1r[r] : q1r[r]) * (p ? p2.x : q2.x); }
      { float e = e1r[r] + e2.y; bool p = e > 0.f;
        s1 = av[r].y * (p ? p1r[r] : q1r[r]) * (p ? p2.y : q2.y); }
      { float e = e1r[r] + e2.z; bool p = e > 0.f;
        s2 = av[r].z * (p ? p1r[r] : q1r[r]) * (p ? p2.z : q2.z); }
      { float e = e1r[r] + e2.w; bool p = e > 0.f;
        s3 = av[r].w * (p ? p1r[r] : q1r[r]) * (p ? p2.w : q2.w); }
      sum[r] += (s0 + s1) + (s2 + s3);
    }
  }
#pragma unroll
  for (int r = 0; r < 4; ++r) {
#pragma unroll
    for (int off = 32; off > 0; off >>= 1) sum[r] += __shfl_down(sum[r], off);
  }
  if (lane == 0) {
#pragma unroll
    for (int r = 0; r < 4; ++r) invrs[c * 2048 + i0 + r] = 1.0f / sum[r];
  }
}

// ---------------------------------------------------------------------------
// K3: hp[k][j] += sum_{i in split} w(i,j,c) * (h[i,k]*invrs[c][i]).
// Block 384 (wave = comp c, lanes = 64 j). Grid (32 j-tiles, 16 i-splits).
// Epilogue merges via atomicAdd (hp pre-zeroed).
__global__ __launch_bounds__(384) void k3_hprime(
    const float* __restrict__ adj0, const float* __restrict__ hcol,
    const float* __restrict__ pack1, const float* __restrict__ pack2,
    const float* __restrict__ invrs, float* __restrict__ hp) {
  __shared__ float sAdj[64 * 64];
  __shared__ float4 sPack[6 * 64];   // e1, p1, q1, 0
  __shared__ float sHS[6 * 64 * 8];  // scaled h, 6 used + 2 pad
  float4* sAdj4 = (float4*)sAdj;
  const float4* adj4 = (const float4*)adj0;
  float4* sHS4 = (float4*)sHS;
  int tid = threadIdx.x;
  int c6 = tid >> 6, jl = tid & 63;
  int j0 = blockIdx.x * 64;
  int j = j0 + jl;
  float e2v = pack2[c6 * 2048 + j];
  float p2v = pack2[(6 + c6) * 2048 + j];
  float q2v = pack2[(12 + c6) * 2048 + j];
  float acc0 = 0.f, acc1 = 0.f, acc2 = 0.f, acc3 = 0.f, acc4 = 0.f, acc5 = 0.f;
  int ibeg = blockIdx.y * 128, iend = ibeg + 128;
  for (int i0 = ibeg; i0 < iend; i0 += 64) {
    __syncthreads();
    for (int idx = tid; idx < 1024; idx += 384) {
      int ii = idx >> 4, c4 = idx & 15;
      sAdj4[ii * 16 + c4] = adj4[(i0 + ii) * 512 + (j0 >> 2) + c4];
    }
    {
      int cc = c6, ii = jl;
      float e1 = pack1[cc * 2048 + i0 + ii];
      float p1 = pack1[(6 + cc) * 2048 + i0 + ii];
      float q1 = pack1[(12 + cc) * 2048 + i0 + ii];
      sPack[cc * 64 + ii] = make_float4(e1, p1, q1, 0.f);
      float iv = invrs[cc * 2048 + i0 + ii];
#pragma unroll
      for (int d = 0; d < 6; ++d)
        sHS[(cc * 64 + ii) * 8 + d] = hcol[(cc * 6 + d) * 2048 + i0 + ii] * iv;
      sHS[(cc * 64 + ii) * 8 + 6] = 0.f;
      sHS[(cc * 64 + ii) * 8 + 7] = 0.f;
    }
    __syncthreads();
#pragma unroll 8
    for (int ii = 0; ii < 64; ++ii) {
      float adjv = sAdj[ii * 64 + jl];
      float4 pk = sPack[c6 * 64 + ii];
      float4 h0 = sHS4[(c6 * 64 + ii) * 2];
      float4 h1 = sHS4[(c6 * 64 + ii) * 2 + 1];
      float e = pk.x + e2v;
      bool pos = e > 0.f;
      float w = adjv * (pos ? pk.y : pk.z) * (pos ? p2v : q2v);
      acc0 += w * h0.x;
      acc1 += w * h0.y;
      acc2 += w * h0.z;
      acc3 += w * h0.w;
      acc4 += w * h1.x;
      acc5 += w * h1.y;
    }
  }
  int kb = c6 * 6;
  atomicAdd(&hp[(kb + 0) * 2048 + j], acc0);
  atomicAdd(&hp[(kb + 1) * 2048 + j], acc1);
  atomicAdd(&hp[(kb + 2) * 2048 + j], acc2);
  atomicAdd(&hp[(kb + 3) * 2048 + j], acc3);
  atomicAdd(&hp[(kb + 4) * 2048 + j], acc4);
  atomicAdd(&hp[(kb + 5) * 2048 + j], acc5);
}

// ---------------------------------------------------------------------------
// K4: elu(hp) -> T[j][32] = {hcY@Wg1, hcO@Wo1}. 32 j per block, grid 64.
__global__ __launch_bounds__(256) void k4_T(
    const float* __restrict__ hp, const float* __restrict__ Wg1,
    const float* __restrict__ Wo1, float* __restrict__ T) {
  __shared__ float sHP[32 * 37];
  __shared__ float sWg[288], sWo[288];
  int tid = threadIdx.x;
  int j0 = blockIdx.x * 32;
  for (int idx = tid; idx < 288; idx += 256) {
    sWg[idx] = Wg1[idx];
    sWo[idx] = Wo1[idx];
  }
  for (int idx = tid; idx < 1152; idx += 256) {
    int r = idx >> 5, jl = idx & 31;
    sHP[jl * 37 + r] = hp[r * 2048 + j0 + jl];
  }
  __syncthreads();
  int jl = tid & 31, wq = tid >> 5;   // wq: gat(2) x colgroup(4)
  int gat = wq >> 2;
  int c0 = (wq & 3) * 4;
  const float* Wp = gat ? sWo : sWg;
  float acc[4];
#pragma unroll
  for (int t = 0; t < 4; ++t) acc[t] = 0.f;
#pragma unroll
  for (int r = 0; r < 18; ++r) {
    float x = sHP[jl * 37 + gat * 18 + r];
    float hc = x > 0.f ? x : __expf(x) - 1.f;
#pragma unroll
    for (int t = 0; t < 4; ++t) acc[t] += hc * Wp[r * 16 + c0 + t];
  }
#pragma unroll
  for (int t = 0; t < 4; ++t) T[(j0 + jl) * 32 + gat * 16 + c0 + t] = acc[t];
}

// ---------------------------------------------------------------------------
// K5: Craw[r][c] += a0[r, kseg] @ T[kseg, c]. 32-row tiles x 16 k-splits
// (kw=128), block 256 = (row 0..31, cg 0..7 of 4 cols). Atomic merge.
__global__ __launch_bounds__(256) void k5_gcn1(
    const float* __restrict__ adj0, const float* __restrict__ T,
    float* __restrict__ Craw) {
  __shared__ float sAtT[64 * 33];  // [k][row], pad 33
  __shared__ float sT[64 * 32];    // [k][c]
  float4* sT4 = (float4*)sT;
  const float4* adj4 = (const float4*)adj0;
  const float4* T4 = (const float4*)T;
  int tid = threadIdx.x;
  int row = tid & 31, cg = tid >> 5;
  int i0 = blockIdx.x * 32;
  int k0 = blockIdx.y * 128;
  float acc0 = 0.f, acc1 = 0.f, acc2 = 0.f, acc3 = 0.f;
  for (int kb = k0; kb < k0 + 128; kb += 64) {
    __syncthreads();
    for (int idx = tid; idx < 512; idx += 256) {
      int r = idx >> 4, kq = idx & 15;
      float4 a = adj4[(i0 + r) * 512 + (kb >> 2) + kq];
      sAtT[(kq * 4 + 0) * 33 + r] = a.x;
      sAtT[(kq * 4 + 1) * 33 + r] = a.y;
      sAtT[(kq * 4 + 2) * 33 + r] = a.z;
      sAtT[(kq * 4 + 3) * 33 + r] = a.w;
    }
    for (int idx = tid; idx < 512; idx += 256) sT4[idx] = T4[kb * 8 + idx];
    __syncthreads();
#pragma unroll 16
    for (int k = 0; k < 64; ++k) {
      float a = sAtT[k * 33 + row];
      float4 t = sT4[k * 8 + cg];
      acc0 += a * t.x;
      acc1 += a * t.y;
      acc2 += a * t.z;
      acc3 += a * t.w;
    }
  }
  float* dst = &Craw[(i0 + row) * 32 + cg * 4];
  atomicAdd(dst + 0, acc0);
  atomicAdd(dst + 1, acc1);
  atomicAdd(dst + 2, acc2);
  atomicAdd(dst + 3, acc3);
}

// ---------------------------------------------------------------------------
// K6: T2[j][4] = {relu(Craw_Y+bg1)@Wg2, relu(Craw_O+bo1)@Wo2}.
// Wave handles 2 j (lane>>5), lanes&31 = cc; shuffle-reduce over 16-groups.
__global__ __launch_bounds__(256) void k6_T2(
    const float* __restrict__ Craw, const float* __restrict__ bg1,
    const float* __restrict__ Wg2, const float* __restrict__ bo1,
    const float* __restrict__ Wo2, float* __restrict__ T2) {
  int tid = threadIdx.x;
  int wave = tid >> 6, lane = tid & 63;
  int j = blockIdx.x * 8 + wave * 2 + (lane >> 5);
  int cl = lane & 31;
  int gat = cl >> 4, cc = cl & 15;
  float x = Craw[j * 32 + cl];
  x += gat ? bo1[cc] : bg1[cc];
  x = x > 0.f ? x : 0.f;
  float wa = gat ? Wo2[cc * 2 + 0] : Wg2[cc * 2 + 0];
  float wb = gat ? Wo2[cc * 2 + 1] : Wg2[cc * 2 + 1];
  float pa = x * wa, pb = x * wb;
#pragma unroll
  for (int m = 8; m > 0; m >>= 1) {
    pa += __shfl_xor(pa, m);
    pb += __shfl_xor(pb, m);
  }
  if (cc == 0) {
    T2[j * 4 + gat * 2 + 0] = pa;
    T2[j * 4 + gat * 2 + 1] = pb;
  }
}

// ---------------------------------------------------------------------------
// K7: final a0 @ T2 (+bias), log_softmax(axis=1) + leaky(0.01).
// Wave per row, grid 512.
__global__ __launch_bounds__(256) void k7_final(
    const float* __restrict__ adj0, const float* __restrict__ T2,
    const float* __restrict__ bg2, const float* __restrict__ bo2,
    float* __restrict__ out) {
  int tid = threadIdx.x;
  int lane = tid & 63, w = tid >> 6;
  int r = blockIdx.x * 4 + w;
  const float4* adj4 = (const float4*)adj0;
  const float4* T24 = (const float4*)T2;
  float4 acc = make_float4(0.f, 0.f, 0.f, 0.f);
#pragma unroll
  for (int it = 0; it < 8; ++it) {
    int k4 = it * 64 + lane;
    float4 av = adj4[r * 512 + k4];
    float4 t0 = T24[k4 * 4 + 0];
    float4 t1 = T24[k4 * 4 + 1];
    float4 t2 = T24[k4 * 4 + 2];
    float4 t3 = T24[k4 * 4 + 3];
    acc.x += av.x * t0.x + av.y * t1.x + av.z * t2.x + av.w * t3.x;
    acc.y += av.x * t0.y + av.y * t1.y + av.z * t2.y + av.w * t3.y;
    acc.z += av.x * t0.z + av.y * t1.z + av.z * t2.z + av.w * t3.z;
    acc.w += av.x * t0.w + av.y * t1.w + av.z * t2.w + av.w * t3.w;
  }
#pragma unroll
  for (int off = 32; off > 0; off >>= 1) {
    acc.x += __shfl_down(acc.x, off);
    acc.y += __shfl_down(acc.y, off);
    acc.z += __shfl_down(acc.z, off);
    acc.w += __shfl_down(acc.w, off);
  }
  if (lane == 0) {
    float y0 = acc.x + bg2[0], y1 = acc.y + bg2[1];
    float m = fmaxf(y0, y1);
    float ls = m + logf(__expf(y0 - m) + __expf(y1 - m));
    out[r * 2 + 0] = y0 - ls;
    out[r * 2 + 1] = y1 - ls;
    float o0 = acc.z + bo2[0], o1 = acc.w + bo2[1];
    out[4096 + r * 2 + 0] = o0 > 0.f ? o0 : 0.01f * o0;
    out[4096 + r * 2 + 1] = o1 > 0.f ? o1 : 0.01f * o1;
  }
}

extern "C" void kernel_launch(void* const* d_in, const int* in_sizes, int n_in,
                              void* d_out, int out_size, void* d_ws, size_t ws_size,
                              hipStream_t stream) {
  const float* node = (const float*)d_in[0];
  const float* uv = (const float*)d_in[1];
  const float* adj = (const float*)d_in[2];  // batch 0 = first 2048*2048
  const float* Wt1 = (const float*)d_in[3];
  const float* at1 = (const float*)d_in[4];
  const float* Wt2 = (const float*)d_in[5];
  const float* at2 = (const float*)d_in[6];
  const float* Wg1 = (const float*)d_in[7];
  const float* bg1 = (const float*)d_in[8];
  const float* Wg2 = (const float*)d_in[9];
  const float* bg2 = (const float*)d_in[10];
  const float* Wo1 = (const float*)d_in[11];
  const float* bo1 = (const float*)d_in[12];
  const float* Wo2 = (const float*)d_in[13];
  const float* bo2 = (const float*)d_in[14];
  float* ws = (float*)d_ws;
  float* hcol = ws;                  // 73728
  float* pack1 = ws + 73728;         // 36864
  float* pack2 = ws + 110592;        // 36864
  float* invrs = ws + 147456;        // 12288
  float* T = ws + 159744;            // 65536
  float* T2 = ws + 225280;           // 8192
  float* hp = ws + 233472;           // 73728 (zeroed)
  float* Craw = ws + 307200;         // 65536 (zeroed)
  float* out = (float*)d_out;

  // zero hp + Craw in one shot (contiguous)
  hipMemsetAsync(hp, 0, (73728 + 65536) * sizeof(float), stream);
  k1_features<<<48, 256, 0, stream>>>(node, uv, Wt1, at1, Wt2, at2, hcol, pack1, pack2);
  k2_rowsum<<<512, 384, 0, stream>>>(adj, pack1, pack2, invrs);
  k3_hprime<<<dim3(32, 16), 384, 0, stream>>>(adj, hcol, pack1, pack2, invrs, hp);
  k4_T<<<64, 256, 0, stream>>>(hp, Wg1, Wo1, T);
  k5_gcn1<<<dim3(64, 16), 256, 0, stream>>>(adj, T, Craw);
  k6_T2<<<256, 256, 0, stream>>>(Craw, bg1, Wg2, bo1, Wo2, T2);
  k7_final<<<512, 256, 0, stream>>>(adj, T2, bg2, bo2, out);
}

// Round 5
// 196.643 us; speedup vs baseline: 1.4106x; 1.0616x over previous
//
#include <hip/hip_runtime.h>
#include <hip/hip_bf16.h>

// GAT x2 (3 heads, E=2048, batch 0 only) + 2-layer GCN, log_softmax / leaky.
// Non-neighbor exp(-30) terms (~1e-13 vs rowsums ~O(1e3)) are dropped.
// Split-K merges via device-scope f32 atomics.
// R5 experiment: k5 converted from barrier-staged LDS tiles to a pure
// streaming dot-product kernel (no LDS / no barriers / deep unroll).

// ---------------------------------------------------------------------------
// K1: per-node features. hcol[36][2048] (comp = gat*18 + head*6 + d),
// pack1/pack2 [18][2048]: rows 0..5 = e, 6..11 = exp(e), 12..17 = exp(0.2e)
__global__ __launch_bounds__(256) void k1_features(
    const float* __restrict__ node, const float* __restrict__ uv,
    const float* __restrict__ Wt1, const float* __restrict__ at1,
    const float* __restrict__ Wt2, const float* __restrict__ at2,
    float* __restrict__ hcol, float* __restrict__ pack1, float* __restrict__ pack2) {
  __shared__ float sW[192];
  __shared__ float sA[12];
  int b = blockIdx.x;
  int g = b / 24;
  int h = (b / 8) % 3;
  int e = (b % 8) * 256 + threadIdx.x;
  const float* W = (g ? Wt2 : Wt1) + h * 192;
  const float* A = (g ? at2 : at1) + h * 12;
  const float* x = (g ? uv : node) + e * 32;
  if (threadIdx.x < 192) sW[threadIdx.x] = W[threadIdx.x];
  if (threadIdx.x < 12) sA[threadIdx.x] = A[threadIdx.x];
  __syncthreads();
  float xv[32];
#pragma unroll
  for (int i = 0; i < 32; ++i) xv[i] = x[i];
  float hv[6];
#pragma unroll
  for (int d = 0; d < 6; ++d) hv[d] = 0.f;
#pragma unroll
  for (int i = 0; i < 32; ++i)
#pragma unroll
    for (int d = 0; d < 6; ++d) hv[d] += xv[i] * sW[i * 6 + d];
  float e1 = 0.f, e2 = 0.f;
#pragma unroll
  for (int d = 0; d < 6; ++d) {
    e1 += hv[d] * sA[d];
    e2 += hv[d] * sA[6 + d];
  }
  int c = g * 3 + h;
#pragma unroll
  for (int d = 0; d < 6; ++d) hcol[(c * 6 + d) * 2048 + e] = hv[d];
  pack1[c * 2048 + e] = e1;
  pack1[(6 + c) * 2048 + e] = __expf(e1);
  pack1[(12 + c) * 2048 + e] = __expf(0.2f * e1);
  pack2[c * 2048 + e] = e2;
  pack2[(6 + c) * 2048 + e] = __expf(e2);
  pack2[(12 + c) * 2048 + e] = __expf(0.2f * e2);
}

// ---------------------------------------------------------------------------
// K2: invrs[c][i] = 1 / sum_j w(i,j,c), w = adj * (pos? p1*p2 : q1*q2).
// Block 384 (wave = comp c), 4 rows per block, lanes sweep j via float4.
__global__ __launch_bounds__(384) void k2_rowsum(
    const float* __restrict__ adj0, const float* __restrict__ pack1,
    const float* __restrict__ pack2, float* __restrict__ invrs) {
  int tid = threadIdx.x;
  int c = tid >> 6, lane = tid & 63;
  int i0 = blockIdx.x * 4;
  const float4* adj4 = (const float4*)adj0;
  const float4* p2_4 = (const float4*)pack2;
  float e1r[4], p1r[4], q1r[4], sum[4];
#pragma unroll
  for (int r = 0; r < 4; ++r) {
    e1r[r] = pack1[c * 2048 + i0 + r];
    p1r[r] = pack1[(6 + c) * 2048 + i0 + r];
    q1r[r] = pack1[(12 + c) * 2048 + i0 + r];
    sum[r] = 0.f;
  }
#pragma unroll
  for (int it = 0; it < 8; ++it) {
    int j4 = it * 64 + lane;
    float4 e2 = p2_4[c * 512 + j4];
    float4 p2 = p2_4[(6 + c) * 512 + j4];
    float4 q2 = p2_4[(12 + c) * 512 + j4];
    float4 av[4];
#pragma unroll
    for (int r = 0; r < 4; ++r) av[r] = adj4[(i0 + r) * 512 + j4];
#pragma unroll
    for (int r = 0; r < 4; ++r) {
      float s0, s1, s2, s3;
      { float e = e1r[r] + e2.x; bool p = e > 0.f;
        s0 = av[r].x * (p ? p1r[r] : q1r[r]) * (p ? p2.x : q2.x); }
      { float e = e1r[r] + e2.y; bool p = e > 0.f;
        s1 = av[r].y * (p ? p1r[r] : q1r[r]) * (p ? p2.y : q2.y); }
      { float e = e1r[r] + e2.z; bool p = e > 0.f;
        s2 = av[r].z * (p ? p1r[r] : q1r[r]) * (p ? p2.z : q2.z); }
      { float e = e1r[r] + e2.w; bool p = e > 0.f;
        s3 = av[r].w * (p ? p1r[r] : q1r[r]) * (p ? p2.w : q2.w); }
      sum[r] += (s0 + s1) + (s2 + s3);
    }
  }
#pragma unroll
  for (int r = 0; r < 4; ++r) {
#pragma unroll
    for (int off = 32; off > 0; off >>= 1) sum[r] += __shfl_down(sum[r], off);
  }
  if (lane == 0) {
#pragma unroll
    for (int r = 0; r < 4; ++r) invrs[c * 2048 + i0 + r] = 1.0f / sum[r];
  }
}

// ---------------------------------------------------------------------------
// K3: hp[k][j] += sum_{i in split} w(i,j,c) * (h[i,k]*invrs[c][i]).
// Block 384 (wave = comp c, lanes = 64 j). Grid (32 j-tiles, 16 i-splits).
// Epilogue merges via atomicAdd (hp pre-zeroed).  [unchanged this round]
__global__ __launch_bounds__(384) void k3_hprime(
    const float* __restrict__ adj0, const float* __restrict__ hcol,
    const float* __restrict__ pack1, const float* __restrict__ pack2,
    const float* __restrict__ invrs, float* __restrict__ hp) {
  __shared__ float sAdj[64 * 64];
  __shared__ float4 sPack[6 * 64];   // e1, p1, q1, 0
  __shared__ float sHS[6 * 64 * 8];  // scaled h, 6 used + 2 pad
  float4* sAdj4 = (float4*)sAdj;
  const float4* adj4 = (const float4*)adj0;
  float4* sHS4 = (float4*)sHS;
  int tid = threadIdx.x;
  int c6 = tid >> 6, jl = tid & 63;
  int j0 = blockIdx.x * 64;
  int j = j0 + jl;
  float e2v = pack2[c6 * 2048 + j];
  float p2v = pack2[(6 + c6) * 2048 + j];
  float q2v = pack2[(12 + c6) * 2048 + j];
  float acc0 = 0.f, acc1 = 0.f, acc2 = 0.f, acc3 = 0.f, acc4 = 0.f, acc5 = 0.f;
  int ibeg = blockIdx.y * 128, iend = ibeg + 128;
  for (int i0 = ibeg; i0 < iend; i0 += 64) {
    __syncthreads();
    for (int idx = tid; idx < 1024; idx += 384) {
      int ii = idx >> 4, c4 = idx & 15;
      sAdj4[ii * 16 + c4] = adj4[(i0 + ii) * 512 + (j0 >> 2) + c4];
    }
    {
      int cc = c6, ii = jl;
      float e1 = pack1[cc * 2048 + i0 + ii];
      float p1 = pack1[(6 + cc) * 2048 + i0 + ii];
      float q1 = pack1[(12 + cc) * 2048 + i0 + ii];
      sPack[cc * 64 + ii] = make_float4(e1, p1, q1, 0.f);
      float iv = invrs[cc * 2048 + i0 + ii];
#pragma unroll
      for (int d = 0; d < 6; ++d)
        sHS[(cc * 64 + ii) * 8 + d] = hcol[(cc * 6 + d) * 2048 + i0 + ii] * iv;
      sHS[(cc * 64 + ii) * 8 + 6] = 0.f;
      sHS[(cc * 64 + ii) * 8 + 7] = 0.f;
    }
    __syncthreads();
#pragma unroll 8
    for (int ii = 0; ii < 64; ++ii) {
      float adjv = sAdj[ii * 64 + jl];
      float4 pk = sPack[c6 * 64 + ii];
      float4 h0 = sHS4[(c6 * 64 + ii) * 2];
      float4 h1 = sHS4[(c6 * 64 + ii) * 2 + 1];
      float e = pk.x + e2v;
      bool pos = e > 0.f;
      float w = adjv * (pos ? pk.y : pk.z) * (pos ? p2v : q2v);
      acc0 += w * h0.x;
      acc1 += w * h0.y;
      acc2 += w * h0.z;
      acc3 += w * h0.w;
      acc4 += w * h1.x;
      acc5 += w * h1.y;
    }
  }
  int kb = c6 * 6;
  atomicAdd(&hp[(kb + 0) * 2048 + j], acc0);
  atomicAdd(&hp[(kb + 1) * 2048 + j], acc1);
  atomicAdd(&hp[(kb + 2) * 2048 + j], acc2);
  atomicAdd(&hp[(kb + 3) * 2048 + j], acc3);
  atomicAdd(&hp[(kb + 4) * 2048 + j], acc4);
  atomicAdd(&hp[(kb + 5) * 2048 + j], acc5);
}

// ---------------------------------------------------------------------------
// K4: elu(hp) -> T[j][32] = {hcY@Wg1, hcO@Wo1}. 32 j per block, grid 64.
__global__ __launch_bounds__(256) void k4_T(
    const float* __restrict__ hp, const float* __restrict__ Wg1,
    const float* __restrict__ Wo1, float* __restrict__ T) {
  __shared__ float sHP[32 * 37];
  __shared__ float sWg[288], sWo[288];
  int tid = threadIdx.x;
  int j0 = blockIdx.x * 32;
  for (int idx = tid; idx < 288; idx += 256) {
    sWg[idx] = Wg1[idx];
    sWo[idx] = Wo1[idx];
  }
  for (int idx = tid; idx < 1152; idx += 256) {
    int r = idx >> 5, jl = idx & 31;
    sHP[jl * 37 + r] = hp[r * 2048 + j0 + jl];
  }
  __syncthreads();
  int jl = tid & 31, wq = tid >> 5;   // wq: gat(2) x colgroup(4)
  int gat = wq >> 2;
  int c0 = (wq & 3) * 4;
  const float* Wp = gat ? sWo : sWg;
  float acc[4];
#pragma unroll
  for (int t = 0; t < 4; ++t) acc[t] = 0.f;
#pragma unroll
  for (int r = 0; r < 18; ++r) {
    float x = sHP[jl * 37 + gat * 18 + r];
    float hc = x > 0.f ? x : __expf(x) - 1.f;
#pragma unroll
    for (int t = 0; t < 4; ++t) acc[t] += hc * Wp[r * 16 + c0 + t];
  }
#pragma unroll
  for (int t = 0; t < 4; ++t) T[(j0 + jl) * 32 + gat * 16 + c0 + t] = acc[t];
}

// ---------------------------------------------------------------------------
// K5 (STREAMING): Craw[r][c] += sum_{k in seg} adj[r][k] * T[k][c].
// Lane = (rh, c): 2 rows per wave, 32 cols. No LDS, no barriers; 512-k
// segment per block with 16-deep load pipelining. Grid (256, 4), atomic merge.
__global__ __launch_bounds__(256) void k5_gcn1(
    const float* __restrict__ adj0, const float* __restrict__ T,
    float* __restrict__ Craw) {
  int tid = threadIdx.x;
  int lane = tid & 63, w = tid >> 6;
  int c = lane & 31, rh = lane >> 5;
  int r = blockIdx.x * 8 + w * 2 + rh;
  int k0 = blockIdx.y * 512;
  const float* arow = adj0 + (size_t)r * 2048 + k0;
  const float* tcol = T + (size_t)k0 * 32 + c;
  float acc = 0.f;
#pragma unroll 16
  for (int k = 0; k < 512; ++k) {
    acc += arow[k] * tcol[k * 32];
  }
  atomicAdd(&Craw[r * 32 + c], acc);
}

// ---------------------------------------------------------------------------
// K6: T2[j][4] = {relu(Craw_Y+bg1)@Wg2, relu(Craw_O+bo1)@Wo2}.
// Wave handles 2 j (lane>>5), lanes&31 = cc; shuffle-reduce over 16-groups.
__global__ __launch_bounds__(256) void k6_T2(
    const float* __restrict__ Craw, const float* __restrict__ bg1,
    const float* __restrict__ Wg2, const float* __restrict__ bo1,
    const float* __restrict__ Wo2, float* __restrict__ T2) {
  int tid = threadIdx.x;
  int wave = tid >> 6, lane = tid & 63;
  int j = blockIdx.x * 8 + wave * 2 + (lane >> 5);
  int cl = lane & 31;
  int gat = cl >> 4, cc = cl & 15;
  float x = Craw[j * 32 + cl];
  x += gat ? bo1[cc] : bg1[cc];
  x = x > 0.f ? x : 0.f;
  float wa = gat ? Wo2[cc * 2 + 0] : Wg2[cc * 2 + 0];
  float wb = gat ? Wo2[cc * 2 + 1] : Wg2[cc * 2 + 1];
  float pa = x * wa, pb = x * wb;
#pragma unroll
  for (int m = 8; m > 0; m >>= 1) {
    pa += __shfl_xor(pa, m);
    pb += __shfl_xor(pb, m);
  }
  if (cc == 0) {
    T2[j * 4 + gat * 2 + 0] = pa;
    T2[j * 4 + gat * 2 + 1] = pb;
  }
}

// ---------------------------------------------------------------------------
// K7: final a0 @ T2 (+bias), log_softmax(axis=1) + leaky(0.01).
// Wave per row, grid 512.
__global__ __launch_bounds__(256) void k7_final(
    const float* __restrict__ adj0, const float* __restrict__ T2,
    const float* __restrict__ bg2, const float* __restrict__ bo2,
    float* __restrict__ out) {
  int tid = threadIdx.x;
  int lane = tid & 63, w = tid >> 6;
  int r = blockIdx.x * 4 + w;
  const float4* adj4 = (const float4*)adj0;
  const float4* T24 = (const float4*)T2;
  float4 acc = make_float4(0.f, 0.f, 0.f, 0.f);
#pragma unroll
  for (int it = 0; it < 8; ++it) {
    int k4 = it * 64 + lane;
    float4 av = adj4[r * 512 + k4];
    float4 t0 = T24[k4 * 4 + 0];
    float4 t1 = T24[k4 * 4 + 1];
    float4 t2 = T24[k4 * 4 + 2];
    float4 t3 = T24[k4 * 4 + 3];
    acc.x += av.x * t0.x + av.y * t1.x + av.z * t2.x + av.w * t3.x;
    acc.y += av.x * t0.y + av.y * t1.y + av.z * t2.y + av.w * t3.y;
    acc.z += av.x * t0.z + av.y * t1.z + av.z * t2.z + av.w * t3.z;
    acc.w += av.x * t0.w + av.y * t1.w + av.z * t2.w + av.w * t3.w;
  }
#pragma unroll
  for (int off = 32; off > 0; off >>= 1) {
    acc.x += __shfl_down(acc.x, off);
    acc.y += __shfl_down(acc.y, off);
    acc.z += __shfl_down(acc.z, off);
    acc.w += __shfl_down(acc.w, off);
  }
  if (lane == 0) {
    float y0 = acc.x + bg2[0], y1 = acc.y + bg2[1];
    float m = fmaxf(y0, y1);
    float ls = m + logf(__expf(y0 - m) + __expf(y1 - m));
    out[r * 2 + 0] = y0 - ls;
    out[r * 2 + 1] = y1 - ls;
    float o0 = acc.z + bo2[0], o1 = acc.w + bo2[1];
    out[4096 + r * 2 + 0] = o0 > 0.f ? o0 : 0.01f * o0;
    out[4096 + r * 2 + 1] = o1 > 0.f ? o1 : 0.01f * o1;
  }
}

extern "C" void kernel_launch(void* const* d_in, const int* in_sizes, int n_in,
                              void* d_out, int out_size, void* d_ws, size_t ws_size,
                              hipStream_t stream) {
  const float* node = (const float*)d_in[0];
  const float* uv = (const float*)d_in[1];
  const float* adj = (const float*)d_in[2];  // batch 0 = first 2048*2048
  const float* Wt1 = (const float*)d_in[3];
  const float* at1 = (const float*)d_in[4];
  const float* Wt2 = (const float*)d_in[5];
  const float* at2 = (const float*)d_in[6];
  const float* Wg1 = (const float*)d_in[7];
  const float* bg1 = (const float*)d_in[8];
  const float* Wg2 = (const float*)d_in[9];
  const float* bg2 = (const float*)d_in[10];
  const float* Wo1 = (const float*)d_in[11];
  const float* bo1 = (const float*)d_in[12];
  const float* Wo2 = (const float*)d_in[13];
  const float* bo2 = (const float*)d_in[14];
  float* ws = (float*)d_ws;
  float* hcol = ws;                  // 73728
  float* pack1 = ws + 73728;         // 36864
  float* pack2 = ws + 110592;        // 36864
  float* invrs = ws + 147456;        // 12288
  float* T = ws + 159744;            // 65536
  float* T2 = ws + 225280;           // 8192
  float* hp = ws + 233472;           // 73728 (zeroed)
  float* Craw = ws + 307200;         // 65536 (zeroed)
  float* out = (float*)d_out;

  // zero hp + Craw in one shot (contiguous)
  hipMemsetAsync(hp, 0, (73728 + 65536) * sizeof(float), stream);
  k1_features<<<48, 256, 0, stream>>>(node, uv, Wt1, at1, Wt2, at2, hcol, pack1, pack2);
  k2_rowsum<<<512, 384, 0, stream>>>(adj, pack1, pack2, invrs);
  k3_hprime<<<dim3(32, 16), 384, 0, stream>>>(adj, hcol, pack1, pack2, invrs, hp);
  k4_T<<<64, 256, 0, stream>>>(hp, Wg1, Wo1, T);
  k5_gcn1<<<dim3(256, 4), 256, 0, stream>>>(adj, T, Craw);
  k6_T2<<<256, 256, 0, stream>>>(Craw, bg1, Wg2, bo1, Wo2, T2);
  k7_final<<<512, 256, 0, stream>>>(adj, T2, bg2, bo2, out);
}